// Round 4
// baseline (104.402 us; speedup 1.0000x reference)
//
#include <hip/hip_runtime.h>
#include <hip/hip_fp16.h>

// Problem: B=2, N=1024, F_in=128, F_out=64
// out[b,i,f] = (1 - deg[b,i]) * xw[b,i,f] + sum_j w[b,i,j]*xw[b,j,f] + bias[f]
//   w[b,i,j] = adj[b,i,j] / max(L1(xw_i, xw_j), 1e-3), deg = row-sum of w
// Diagonal w_ii cancels identically in the output -> excluded from w and deg.
//
// R5: 64x64 (i,j) tiles, grid 512. Phase 1: packed-f16 L1 distances with 4x4
// register blocking + XOR-swizzled LDS (balanced banks). Phase 2: f16 MFMA.
// R6: divide -> v_rcp_f32 * mul; finish vectorized 2-wide.
// R7: finish kernel FOLDED into fused kernel via last-arriver election
//     (device-scope atomicAdd counter per (b,i-tile); election on old%16==15
//     works for arbitrary counter garbage -> no memset node needed).
//     2 dispatches total; finish overlaps the tail of fused compute.
// R8/R9: identical resubmissions (R7/R8 never ran: GPU acquisition timeouts).

#define JS 16
#define HSTR 72    // f16 row stride: 144 B (16B-aligned; swizzle balances banks)

typedef _Float16 half4_t __attribute__((ext_vector_type(4)));
typedef _Float16 half8_t __attribute__((ext_vector_type(8)));
typedef float    f32x4_t __attribute__((ext_vector_type(4)));

// ---------------- Kernel 1: xw = x @ W; emit f32, f16, f16-transposed ----
__global__ __launch_bounds__(256) void gemm_xw(const float* __restrict__ x,
                                               const float* __restrict__ w,
                                               float* __restrict__ xw,
                                               __half* __restrict__ xwh,
                                               __half* __restrict__ xwt) {
    __shared__ float ws_[128 * 64];   // 32 KB
    __shared__ float xs[8 * 132];
    __shared__ __half ts[8 * 64];     // transpose staging
    const int tid = threadIdx.x;
    const int r0  = blockIdx.x * 8;   // 256 blocks x 8 rows

#pragma unroll
    for (int e = tid; e < 2048; e += 256)
        ((float4*)ws_)[e] = ((const float4*)w)[e];
    {
        int row = tid >> 5, c = tid & 31;
        float4 v = *(const float4*)&x[(size_t)(r0 + row) * 128 + c * 4];
        *(float4*)&xs[row * 132 + c * 4] = v;
    }
    __syncthreads();

    const int rl = tid >> 5;   // 0..7
    const int fg = tid & 31;   // 2 features
    float2 acc = {0.f, 0.f};
#pragma unroll
    for (int k4 = 0; k4 < 32; ++k4) {
        float4 xv = *(const float4*)&xs[rl * 132 + k4 * 4];
        const float* xp = &xv.x;
#pragma unroll
        for (int m = 0; m < 4; ++m) {
            float2 wv = *(const float2*)&ws_[(k4 * 4 + m) * 64 + 2 * fg];
            acc.x += xp[m] * wv.x; acc.y += xp[m] * wv.y;
        }
    }
    size_t o = (size_t)(r0 + rl) * 64 + 2 * fg;
    *(float2*)&xw[o] = acc;
    __half2 h2 = __floats2half2_rn(acc.x, acc.y);
    *(__half2*)&xwh[o] = h2;
    *(__half2*)&ts[rl * 64 + 2 * fg] = h2;
    __syncthreads();

    if (tid < 64) {
        const int f = tid;
        const int b = r0 >> 10;
        const int n0 = r0 & 1023;
        __half hv[8];
#pragma unroll
        for (int r = 0; r < 8; ++r) hv[r] = ts[r * 64 + f];
        *(half8_t*)&xwt[((size_t)(b * 64 + f)) * 1024 + n0] = *(half8_t*)hv;
    }
}

// ---------------- Kernel 2: fused distances + MFMA + elected finish ----------
__global__ __launch_bounds__(256) void fused_gtv_fin(const __half* __restrict__ xwh,
                                                     const __half* __restrict__ xwt,
                                                     const float* __restrict__ adj,
                                                     __half* __restrict__ part,
                                                     float* __restrict__ pdeg,
                                                     const float* __restrict__ xw,
                                                     const float* __restrict__ bias,
                                                     float* __restrict__ out,
                                                     unsigned* __restrict__ done) {
    __shared__ __half xih[64 * HSTR];   // 9 KB [i][f], 16B-block swizzled
    __shared__ __half xjh[64 * HSTR];   // 9 KB [j][f], swizzled
    __shared__ __half xjt[64 * HSTR];   // 9 KB [f][j], linear (MFMA B)
    __shared__ __half wt [64 * HSTR];   // 9 KB [i][j], linear (MFMA A)

    const int tid = threadIdx.x;
    const int bx  = blockIdx.x;
    const int js  = bx & 15;
    const int it  = (bx >> 4) & 15;
    const int b   = bx >> 8;
    const int i0  = it * 64;
    const int j0  = js * 64;

    const __half* xhb = xwh + (size_t)b * 65536;
    const __half* xtb = xwt + (size_t)b * 65536;
    const float*  adjb = adj + (size_t)b * 1048576;

    const int ty = tid >> 4;   // 0..15 -> i rows 4ty..4ty+3
    const int tx = tid & 15;   // 0..15 -> j cols 4tx..4tx+3

    // prefetch adj 4x4 block (16 lanes x 16B = 256B contiguous per row)
    float4 av[4];
#pragma unroll
    for (int r = 0; r < 4; ++r)
        av[r] = *(const float4*)&adjb[(size_t)(i0 + 4 * ty + r) * 1024 + j0 + 4 * tx];

    // stage xih/xjh (swizzled) + xjt (linear): 512 x 16B each, 2 per thread
#pragma unroll
    for (int e = tid; e < 512; e += 256) {
        int row = e >> 3, cb = e & 7;
        int sc = ((cb ^ ((row >> 2) & 7)) << 3);
        float4 vi = *(const float4*)&xhb[(i0 + row) * 64 + cb * 8];
        *(float4*)&xih[row * HSTR + sc] = vi;
        float4 vj = *(const float4*)&xhb[(j0 + row) * 64 + cb * 8];
        *(float4*)&xjh[row * HSTR + sc] = vj;
        float4 vt = *(const float4*)&xtb[row * 1024 + j0 + cb * 8];  // row = f
        *(float4*)&xjt[row * HSTR + cb * 8] = vt;
    }
    __syncthreads();

    // ---- phase 1: 4x4 pairwise L1 distances, packed f16 ----
    __half2 acc[4][4];
#pragma unroll
    for (int r = 0; r < 4; ++r)
#pragma unroll
        for (int q = 0; q < 4; ++q) acc[r][q] = __floats2half2_rn(0.f, 0.f);

#pragma unroll
    for (int c = 0; c < 8; ++c) {
        const int ca = ((c ^ (ty & 7)) << 3);
        const int cb = ((c ^ (tx & 7)) << 3);
        float4 a[4], bb[4];
#pragma unroll
        for (int r = 0; r < 4; ++r)
            a[r] = *(const float4*)&xih[(4 * ty + r) * HSTR + ca];
#pragma unroll
        for (int q = 0; q < 4; ++q)
            bb[q] = *(const float4*)&xjh[(4 * tx + q) * HSTR + cb];
#pragma unroll
        for (int r = 0; r < 4; ++r) {
            const __half2* pa = (const __half2*)&a[r];
#pragma unroll
            for (int q = 0; q < 4; ++q) {
                const __half2* pb = (const __half2*)&bb[q];
#pragma unroll
                for (int m = 0; m < 4; ++m)
                    acc[r][q] = __hadd2(acc[r][q], __habs2(__hsub2(pa[m], pb[m])));
            }
        }
    }

    // w = adj * rcp(max(d,1e-3)), diag excluded; write f16 wt[i][j]; deg via shfl
    float dsum[4];
#pragma unroll
    for (int r = 0; r < 4; ++r) {
        const int gi = i0 + 4 * ty + r;
        float wv[4];
        dsum[r] = 0.f;
#pragma unroll
        for (int q = 0; q < 4; ++q) {
            float d = __low2float(acc[r][q]) + __high2float(acc[r][q]);
            float inv = __builtin_amdgcn_rcpf(fmaxf(d, 1e-3f));
            float v = (&av[r].x)[q] * inv;
            wv[q] = (gi == j0 + 4 * tx + q) ? 0.f : v;
            dsum[r] += wv[q];
        }
        float2 packed;
        ((__half2*)&packed)[0] = __floats2half2_rn(wv[0], wv[1]);
        ((__half2*)&packed)[1] = __floats2half2_rn(wv[2], wv[3]);
        *(float2*)&wt[(4 * ty + r) * HSTR + 4 * tx] = packed;
    }
#pragma unroll
    for (int r = 0; r < 4; ++r) {
#pragma unroll
        for (int m = 1; m < 16; m <<= 1)
            dsum[r] += __shfl_xor(dsum[r], m, 16);
    }
    if (tx == 0) {
#pragma unroll
        for (int r = 0; r < 4; ++r)
            pdeg[(js * 2 + b) * 1024 + i0 + 4 * ty + r] = dsum[r];
    }
    __syncthreads();

    // ---- phase 2: MFMA  P[64x64] = W[64xj64] x Xj[j64xf64] ----
    const int wv_  = tid >> 6;   // wave = m-tile
    const int lane = tid & 63;
    const int quad = lane >> 4;
    const int l15  = lane & 15;

    f32x4_t c[4] = {{0,0,0,0},{0,0,0,0},{0,0,0,0},{0,0,0,0}};
    half8_t a0 = *(half8_t*)&wt[(wv_ * 16 + l15) * HSTR + quad * 8];
    half8_t a1 = *(half8_t*)&wt[(wv_ * 16 + l15) * HSTR + 32 + quad * 8];
#pragma unroll
    for (int n = 0; n < 4; ++n) {
        half8_t b0 = *(half8_t*)&xjt[(n * 16 + l15) * HSTR + quad * 8];
        half8_t b1 = *(half8_t*)&xjt[(n * 16 + l15) * HSTR + 32 + quad * 8];
        c[n] = __builtin_amdgcn_mfma_f32_16x16x32_f16(a0, b0, c[n], 0, 0, 0);
        c[n] = __builtin_amdgcn_mfma_f32_16x16x32_f16(a1, b1, c[n], 0, 0, 0);
    }

    // epilogue: C row = wv_*16 + quad*4 + r, col = n*16 + l15
    const size_t slot = (size_t)(js * 2 + b) * 65536;
#pragma unroll
    for (int n = 0; n < 4; ++n)
#pragma unroll
        for (int r = 0; r < 4; ++r) {
            int row = wv_ * 16 + quad * 4 + r;
            part[slot + (i0 + row) * 64 + n * 16 + l15] = __float2half(c[n][r]);
        }

    // ---- last-arriver election for the finish of this (b, i-tile) ----
    // barrier drains this block's part/pdeg stores (vmcnt 0 before s_barrier);
    // release fence makes them device-visible before the count.
    __syncthreads();
    __shared__ int elect;
    if (tid == 0) {
        __threadfence();  // release: flush our writes to the coherence point
        unsigned old = atomicAdd(&done[b * 16 + it], 1u);  // device scope
        elect = ((old & 15u) == 15u);  // exactly one arrival per launch hits 15 mod 16
    }
    __syncthreads();
    if (!elect) return;
    __threadfence();      // acquire: invalidate stale caches before reading peers' data

    // ---- elected finish: out rows i0..i0+63 for batch b ----
    const float2*  xw2   = (const float2*)xw;
    const float2*  bias2 = (const float2*)bias;
    const __half2* p2    = (const __half2*)part;
    float2*        out2  = (float2*)out;
#pragma unroll 2
    for (int k = 0; k < 8; ++k) {
        int e   = tid + k * 256;   // 0..2047 float2 elements of the 64x64 tile
        int row = e >> 5;
        int f2  = e & 31;
        int n   = i0 + row;
        size_t gr = (size_t)b * 1024 + n;
        float sx = 0.f, sy = 0.f, dg = 0.f;
#pragma unroll
        for (int q = 0; q < JS; ++q) {
            int sl = q * 2 + b;
            __half2 h = p2[(size_t)sl * 32768 + (size_t)n * 32 + f2];
            float2 f = __half22float2(h);
            sx += f.x; sy += f.y;
            dg += pdeg[sl * 1024 + n];
        }
        float2 xv = xw2[gr * 32 + f2];
        float2 bv = bias2[f2];
        float id = 1.f - dg;
        float2 o;
        o.x = sx + id * xv.x + bv.x;
        o.y = sy + id * xv.y + bv.y;
        out2[gr * 32 + f2] = o;
    }
}

// ---------------- Fallback path (small workspace): atomic variant -------------
__global__ __launch_bounds__(256) void fused_gtv_atomic(const __half* __restrict__ xwh,
                                                        const __half* __restrict__ xwt,
                                                        const float* __restrict__ adj,
                                                        float* __restrict__ aout,
                                                        float* __restrict__ pdeg) {
    __shared__ __half xih[64 * HSTR];
    __shared__ __half xjh[64 * HSTR];
    __shared__ __half xjt[64 * HSTR];
    __shared__ __half wt [64 * HSTR];

    const int tid = threadIdx.x;
    const int bx  = blockIdx.x;
    const int js  = bx & 15;
    const int it  = (bx >> 4) & 15;
    const int b   = bx >> 8;
    const int i0  = it * 64;
    const int j0  = js * 64;

    const __half* xhb = xwh + (size_t)b * 65536;
    const __half* xtb = xwt + (size_t)b * 65536;
    const float*  adjb = adj + (size_t)b * 1048576;

    const int ty = tid >> 4;
    const int tx = tid & 15;

    float4 av[4];
#pragma unroll
    for (int r = 0; r < 4; ++r)
        av[r] = *(const float4*)&adjb[(size_t)(i0 + 4 * ty + r) * 1024 + j0 + 4 * tx];

#pragma unroll
    for (int e = tid; e < 512; e += 256) {
        int row = e >> 3, cb = e & 7;
        int sc = ((cb ^ ((row >> 2) & 7)) << 3);
        float4 vi = *(const float4*)&xhb[(i0 + row) * 64 + cb * 8];
        *(float4*)&xih[row * HSTR + sc] = vi;
        float4 vj = *(const float4*)&xhb[(j0 + row) * 64 + cb * 8];
        *(float4*)&xjh[row * HSTR + sc] = vj;
        float4 vt = *(const float4*)&xtb[row * 1024 + j0 + cb * 8];
        *(float4*)&xjt[row * HSTR + cb * 8] = vt;
    }
    __syncthreads();

    __half2 acc[4][4];
#pragma unroll
    for (int r = 0; r < 4; ++r)
#pragma unroll
        for (int q = 0; q < 4; ++q) acc[r][q] = __floats2half2_rn(0.f, 0.f);

#pragma unroll
    for (int c = 0; c < 8; ++c) {
        const int ca = ((c ^ (ty & 7)) << 3);
        const int cb = ((c ^ (tx & 7)) << 3);
        float4 a[4], bb[4];
#pragma unroll
        for (int r = 0; r < 4; ++r)
            a[r] = *(const float4*)&xih[(4 * ty + r) * HSTR + ca];
#pragma unroll
        for (int q = 0; q < 4; ++q)
            bb[q] = *(const float4*)&xjh[(4 * tx + q) * HSTR + cb];
#pragma unroll
        for (int r = 0; r < 4; ++r) {
            const __half2* pa = (const __half2*)&a[r];
#pragma unroll
            for (int q = 0; q < 4; ++q) {
                const __half2* pb = (const __half2*)&bb[q];
#pragma unroll
                for (int m = 0; m < 4; ++m)
                    acc[r][q] = __hadd2(acc[r][q], __habs2(__hsub2(pa[m], pb[m])));
            }
        }
    }

    float dsum[4];
#pragma unroll
    for (int r = 0; r < 4; ++r) {
        const int gi = i0 + 4 * ty + r;
        float wv[4];
        dsum[r] = 0.f;
#pragma unroll
        for (int q = 0; q < 4; ++q) {
            float d = __low2float(acc[r][q]) + __high2float(acc[r][q]);
            float inv = __builtin_amdgcn_rcpf(fmaxf(d, 1e-3f));
            float v = (&av[r].x)[q] * inv;
            wv[q] = (gi == j0 + 4 * tx + q) ? 0.f : v;
            dsum[r] += wv[q];
        }
        float2 packed;
        ((__half2*)&packed)[0] = __floats2half2_rn(wv[0], wv[1]);
        ((__half2*)&packed)[1] = __floats2half2_rn(wv[2], wv[3]);
        *(float2*)&wt[(4 * ty + r) * HSTR + 4 * tx] = packed;
    }
#pragma unroll
    for (int r = 0; r < 4; ++r) {
#pragma unroll
        for (int m = 1; m < 16; m <<= 1)
            dsum[r] += __shfl_xor(dsum[r], m, 16);
    }
    if (tx == 0) {
#pragma unroll
        for (int r = 0; r < 4; ++r)
            atomicAdd(&pdeg[b * 1024 + i0 + 4 * ty + r], dsum[r]);
    }
    __syncthreads();

    const int wv_  = tid >> 6;
    const int lane = tid & 63;
    const int quad = lane >> 4;
    const int l15  = lane & 15;

    f32x4_t c[4] = {{0,0,0,0},{0,0,0,0},{0,0,0,0},{0,0,0,0}};
    half8_t a0 = *(half8_t*)&wt[(wv_ * 16 + l15) * HSTR + quad * 8];
    half8_t a1 = *(half8_t*)&wt[(wv_ * 16 + l15) * HSTR + 32 + quad * 8];
#pragma unroll
    for (int n = 0; n < 4; ++n) {
        half8_t b0 = *(half8_t*)&xjt[(n * 16 + l15) * HSTR + quad * 8];
        half8_t b1 = *(half8_t*)&xjt[(n * 16 + l15) * HSTR + 32 + quad * 8];
        c[n] = __builtin_amdgcn_mfma_f32_16x16x32_f16(a0, b0, c[n], 0, 0, 0);
        c[n] = __builtin_amdgcn_mfma_f32_16x16x32_f16(a1, b1, c[n], 0, 0, 0);
    }

#pragma unroll
    for (int n = 0; n < 4; ++n)
#pragma unroll
        for (int r = 0; r < 4; ++r) {
            int row = wv_ * 16 + quad * 4 + r;
            atomicAdd(&aout[((size_t)b * 1024 + i0 + row) * 64 + n * 16 + l15], c[n][r]);
        }
}

__global__ __launch_bounds__(256) void finish_gtv_atomic(const float* __restrict__ xw,
                                                         const float* __restrict__ pdeg,
                                                         const float* __restrict__ bias,
                                                         float* __restrict__ out) {
    int idx = blockIdx.x * 256 + threadIdx.x;  // 0..131071
    int f = idx & 63;
    int r = idx >> 6;           // b*1024 + n
    out[idx] = out[idx] + (1.f - pdeg[r]) * xw[idx] + bias[f];
}

extern "C" void kernel_launch(void* const* d_in, const int* in_sizes, int n_in,
                              void* d_out, int out_size, void* d_ws, size_t ws_size,
                              hipStream_t stream) {
    const float* x    = (const float*)d_in[0];   // [2,1024,128]
    const float* adj  = (const float*)d_in[1];   // [2,1024,1024]
    const float* w    = (const float*)d_in[2];   // [128,64]
    const float* bias = (const float*)d_in[3];   // [64]
    float* out = (float*)d_out;                  // [2,1024,64]

    char* wsb = (char*)d_ws;
    float*    xw   = (float*)wsb;                      // 512 KB
    __half*   xwh  = (__half*)(wsb + 512 * 1024);      // 256 KB  [b][n][f]
    __half*   xwt  = (__half*)(wsb + 768 * 1024);      // 256 KB  [b][f][n]
    float*    pdeg = (float*)(wsb + 1024 * 1024);      // 128 KB (32 x 1024)
    __half*   part = (__half*)(wsb + 1152 * 1024);     // 4 MB  (32 x 65536 f16)
    unsigned* done = (unsigned*)(wsb + 5248 * 1024);   // 128 B (32 counters)
    const size_t NEED = 5248 * 1024 + 128;

    gemm_xw<<<256, 256, 0, stream>>>(x, w, xw, xwh, xwt);

    if (ws_size >= NEED) {
        // counters need no init: each launch adds exactly 16 per slot, so the
        // election (old % 16 == 15) fires exactly once regardless of start value.
        fused_gtv_fin<<<512, 256, 0, stream>>>(xwh, xwt, adj, part, pdeg,
                                               xw, bias, out, done);
    } else {
        hipMemsetAsync(out, 0, 2 * 1024 * 64 * sizeof(float), stream);
        hipMemsetAsync(pdeg, 0, 2 * 1024 * sizeof(float), stream);
        fused_gtv_atomic<<<512, 256, 0, stream>>>(xwh, xwt, adj, out, pdeg);
        finish_gtv_atomic<<<512, 256, 0, stream>>>(xw, pdeg, bias, out);
    }
}

// Round 5
// 86.309 us; speedup vs baseline: 1.2096x; 1.2096x over previous
//
#include <hip/hip_runtime.h>
#include <hip/hip_fp16.h>

// Problem: B=2, N=1024, F_in=128, F_out=64
// out[b,i,f] = (1 - deg[b,i]) * xw[b,i,f] + sum_j w[b,i,j]*xw[b,j,f] + bias[f]
//   w[b,i,j] = adj[b,i,j] / max(L1(xw_i, xw_j), 1e-3), deg = row-sum of w
// Diagonal w_ii cancels identically in the output -> excluded from w and deg.
//
// R7 post-mortem: last-arriver election + device fences regressed 81.6 -> 104.4 us
// (L2-writeback fences + cold straggler tail). REVERTED.
// R10: row-owner restructure. Each block owns 4 output rows and sweeps ALL j:
//   - distances vs all 1024 j (xwh read from global/L2, 4x4-blocked in regs)
//   - W row complete in LDS (16 x 1024 f16, rows 4..15 zeroed for M=16 MFMA)
//   - deg complete in-block (shfl + tiny LDS) -> no pdeg roundtrip
//   - P = W x XW via K=1024 MFMA chain, f32 accumulation (no f16 part quant)
//   - epilogue writes final out directly.
// Eliminates: part buffer (8 MB HBM roundtrip), pdeg, finish kernel, all fences.
// 2 dispatches, no cross-block communication at all.

#define WSTR 1032   // wt row stride in halves (1024 + 8 pad)

typedef _Float16 half8_t __attribute__((ext_vector_type(8)));
typedef float    f32x4_t __attribute__((ext_vector_type(4)));

// ---------------- Kernel 1: xw = x @ W; emit f32, f16, f16-transposed ----
__global__ __launch_bounds__(256) void gemm_xw(const float* __restrict__ x,
                                               const float* __restrict__ w,
                                               float* __restrict__ xw,
                                               __half* __restrict__ xwh,
                                               __half* __restrict__ xwt) {
    __shared__ float ws_[128 * 64];   // 32 KB
    __shared__ float xs[8 * 132];
    __shared__ __half ts[8 * 64];     // transpose staging
    const int tid = threadIdx.x;
    const int r0  = blockIdx.x * 8;   // 256 blocks x 8 rows

#pragma unroll
    for (int e = tid; e < 2048; e += 256)
        ((float4*)ws_)[e] = ((const float4*)w)[e];
    {
        int row = tid >> 5, c = tid & 31;
        float4 v = *(const float4*)&x[(size_t)(r0 + row) * 128 + c * 4];
        *(float4*)&xs[row * 132 + c * 4] = v;
    }
    __syncthreads();

    const int rl = tid >> 5;   // 0..7
    const int fg = tid & 31;   // 2 features
    float2 acc = {0.f, 0.f};
#pragma unroll
    for (int k4 = 0; k4 < 32; ++k4) {
        float4 xv = *(const float4*)&xs[rl * 132 + k4 * 4];
        const float* xp = &xv.x;
#pragma unroll
        for (int m = 0; m < 4; ++m) {
            float2 wv = *(const float2*)&ws_[(k4 * 4 + m) * 64 + 2 * fg];
            acc.x += xp[m] * wv.x; acc.y += xp[m] * wv.y;
        }
    }
    size_t o = (size_t)(r0 + rl) * 64 + 2 * fg;
    *(float2*)&xw[o] = acc;
    __half2 h2 = __floats2half2_rn(acc.x, acc.y);
    *(__half2*)&xwh[o] = h2;
    *(__half2*)&ts[rl * 64 + 2 * fg] = h2;
    __syncthreads();

    if (tid < 64) {
        const int f = tid;
        const int b = r0 >> 10;
        const int n0 = r0 & 1023;
        __half hv[8];
#pragma unroll
        for (int r = 0; r < 8; ++r) hv[r] = ts[r * 64 + f];
        *(half8_t*)&xwt[((size_t)(b * 64 + f)) * 1024 + n0] = *(half8_t*)hv;
    }
}

// ---------------- Kernel 2: row-owner fused GTV -----------------------------
// Block = (b, 4 output rows). 256 threads, grid 512 (2 blocks/CU).
__global__ __launch_bounds__(256) void fused_rows(const __half* __restrict__ xwh,
                                                  const __half* __restrict__ xwt,
                                                  const float* __restrict__ adj,
                                                  const float* __restrict__ xw,
                                                  const float* __restrict__ bias,
                                                  float* __restrict__ out) {
    __shared__ __half xih[4 * 64];      // 4 i-rows of features (broadcast reads)
    __shared__ __half wt[16 * WSTR];    // 33 KB: W rows 0..3 + zero rows 4..15
    __shared__ float  ps[4 * 68];       // P staging rows x f (pad 68)
    __shared__ float  dpart[16];        // [wave][row] deg partials

    const int tid  = threadIdx.x;
    const int bx   = blockIdx.x;
    const int b    = bx >> 8;           // 0..1
    const int i0   = (bx & 255) * 4;    // 0..1020
    const int w_   = tid >> 6;          // wave 0..3
    const int lane = tid & 63;

    const __half* xb = xwh + (size_t)b * 65536;

    // ---- stage: xih (4 rows) + zero wt rows 4..15 (for M=16 MFMA A) ----
    if (tid < 32) {
        int row = tid >> 3, cb = tid & 7;
        *(float4*)&xih[row * 64 + cb * 8] =
            *(const float4*)&xb[(i0 + row) * 64 + cb * 8];
    }
    {
        float4 z = {0.f, 0.f, 0.f, 0.f};
        float4* wz = (float4*)&wt[4 * WSTR];     // 12 rows x WSTR halves
#pragma unroll 2
        for (int e = tid; e < 1548; e += 256) wz[e] = z;   // 12*1032*2/16
    }
    __syncthreads();

    // ---- distances: this thread owns j = 4*tid .. 4*tid+3, all 4 i-rows ----
    float4 av[4];
#pragma unroll
    for (int r = 0; r < 4; ++r)
        av[r] = *(const float4*)&adj[(size_t)b * 1048576 +
                                     (size_t)(i0 + r) * 1024 + 4 * tid];

    __half2 acc[4][4];
#pragma unroll
    for (int r = 0; r < 4; ++r)
#pragma unroll
        for (int q = 0; q < 4; ++q) acc[r][q] = __floats2half2_rn(0.f, 0.f);

#pragma unroll
    for (int q = 0; q < 4; ++q) {
        // full feature row of j = 4*tid+q (128 B, 2 cache lines, streamed)
        float4 bj[8];
#pragma unroll
        for (int cb = 0; cb < 8; ++cb)
            bj[cb] = *(const float4*)&xb[(size_t)(4 * tid + q) * 64 + cb * 8];
#pragma unroll
        for (int cb = 0; cb < 8; ++cb) {
            const __half2* pb = (const __half2*)&bj[cb];
#pragma unroll
            for (int r = 0; r < 4; ++r) {
                float4 a = *(const float4*)&xih[r * 64 + cb * 8];  // broadcast
                const __half2* pa = (const __half2*)&a;
#pragma unroll
                for (int m = 0; m < 4; ++m)
                    acc[r][q] = __hadd2(acc[r][q], __habs2(__hsub2(pa[m], pb[m])));
            }
        }
    }

    // ---- W = adj * rcp(max(d,1e-3)), diag zero; write wt; deg partials ----
    float dsum[4] = {0.f, 0.f, 0.f, 0.f};
#pragma unroll
    for (int r = 0; r < 4; ++r) {
        const int gi = i0 + r;
        float wv[4];
#pragma unroll
        for (int q = 0; q < 4; ++q) {
            float d = __low2float(acc[r][q]) + __high2float(acc[r][q]);
            float inv = __builtin_amdgcn_rcpf(fmaxf(d, 1e-3f));
            float v = (&av[r].x)[q] * inv;
            wv[q] = (gi == 4 * tid + q) ? 0.f : v;
            dsum[r] += wv[q];
        }
        float2 packed;
        ((__half2*)&packed)[0] = __floats2half2_rn(wv[0], wv[1]);
        ((__half2*)&packed)[1] = __floats2half2_rn(wv[2], wv[3]);
        *(float2*)&wt[r * WSTR + 4 * tid] = packed;
    }
    // deg: reduce over all 64 lanes (each lane holds 4 distinct j), then LDS
#pragma unroll
    for (int r = 0; r < 4; ++r) {
#pragma unroll
        for (int m = 1; m < 64; m <<= 1)
            dsum[r] += __shfl_xor(dsum[r], m, 64);
    }
    if (lane == 0) {
#pragma unroll
        for (int r = 0; r < 4; ++r) dpart[w_ * 4 + r] = dsum[r];
    }
    __syncthreads();

    // ---- MFMA: P[16x64] = W[16x1024] x XW[1024x64], K-chain of 32 ----
    // wave w_ owns f-cols w_*16 .. w_*16+15; B streams from xwt (L2-resident)
    const int quad = lane >> 4;
    const int l15  = lane & 15;
    const __half* bt = xwt + (size_t)b * 65536 + (size_t)(w_ * 16 + l15) * 1024;

    f32x4_t c = {0.f, 0.f, 0.f, 0.f};
#pragma unroll 8
    for (int kc = 0; kc < 32; ++kc) {
        half8_t af = *(const half8_t*)&wt[l15 * WSTR + kc * 32 + quad * 8];
        half8_t bf = *(const half8_t*)&bt[kc * 32 + quad * 8];
        c = __builtin_amdgcn_mfma_f32_16x16x32_f16(af, bf, c, 0, 0, 0);
    }
    // C row = quad*4 + r (rows 0..3 valid -> quad 0), col = w_*16 + l15
    if (quad == 0) {
#pragma unroll
        for (int r = 0; r < 4; ++r) ps[r * 68 + w_ * 16 + l15] = c[r];
    }
    __syncthreads();

    // ---- epilogue: out = (1-deg)*xw + P + bias ----
    {
        int row = tid >> 6;           // 0..3
        int f   = tid & 63;
        float deg = dpart[row] + dpart[4 + row] + dpart[8 + row] + dpart[12 + row];
        size_t o = ((size_t)b * 1024 + i0 + row) * 64 + f;
        out[o] = (1.f - deg) * xw[o] + ps[row * 68 + f] + bias[f];
    }
}

extern "C" void kernel_launch(void* const* d_in, const int* in_sizes, int n_in,
                              void* d_out, int out_size, void* d_ws, size_t ws_size,
                              hipStream_t stream) {
    const float* x    = (const float*)d_in[0];   // [2,1024,128]
    const float* adj  = (const float*)d_in[1];   // [2,1024,1024]
    const float* w    = (const float*)d_in[2];   // [128,64]
    const float* bias = (const float*)d_in[3];   // [64]
    float* out = (float*)d_out;                  // [2,1024,64]

    char* wsb = (char*)d_ws;
    float*  xw  = (float*)wsb;                   // 512 KB [b][n][f] f32
    __half* xwh = (__half*)(wsb + 512 * 1024);   // 256 KB [b][n][f] f16
    __half* xwt = (__half*)(wsb + 768 * 1024);   // 256 KB [b][f][n] f16

    gemm_xw<<<256, 256, 0, stream>>>(x, w, xw, xwh, xwt);
    fused_rows<<<512, 256, 0, stream>>>(xwh, xwt, adj, xw, bias, out);
}

// Round 7
// 81.922 us; speedup vs baseline: 1.2744x; 1.0536x over previous
//
#include <hip/hip_runtime.h>
#include <hip/hip_fp16.h>

// Problem: B=2, N=1024, F_in=128, F_out=64
// out[b,i,f] = (1 - deg[b,i]) * xw[b,i,f] + sum_j w[b,i,j]*xw[b,j,f] + bias[f]
//   w[b,i,j] = adj[b,i,j] / max(L1(xw_i, xw_j), 1e-3), deg = row-sum of w
// Diagonal w_ii cancels identically in the output -> excluded from w and deg.
//
// R6 (verified 81.6us): 64x64 tiles, grid 512 (2 blocks/CU), 3 dispatches.
// R7 (election fold): 104.4us REGRESSION - L2-writeback fences. Reverted.
// R10 (row-owner): 86.3us REGRESSION - uncoalesced global in inner loop. Reverted.
// R11: R6 body re-parameterized for OCCUPANCY: i-tile 64->32, grid 1024.
//   LDS 36->27.6 KB/block -> 4 blocks/CU (16 waves/CU, 4/SIMD), double the
//   latency-hiding of R6 at identical total work. part/pdeg/finish unchanged.
//   Theory: measured deltas are ~5-10x the instruction-count model => kernel
//   is latency-exposed at 2 waves/SIMD, not VALU-throughput-bound.
// R12: identical resubmission (R11 never ran: GPU acquisition timeout).

#define JS 16
#define HSTR 72    // f16 row stride: 144 B (16B-aligned; swizzle balances banks)

typedef _Float16 half8_t __attribute__((ext_vector_type(8)));
typedef float    f32x4_t __attribute__((ext_vector_type(4)));

// ---------------- Kernel 1: xw = x @ W; emit f32, f16, f16-transposed ----
__global__ __launch_bounds__(256) void gemm_xw(const float* __restrict__ x,
                                               const float* __restrict__ w,
                                               float* __restrict__ xw,
                                               __half* __restrict__ xwh,
                                               __half* __restrict__ xwt) {
    __shared__ float ws_[128 * 64];   // 32 KB
    __shared__ float xs[8 * 132];
    __shared__ __half ts[8 * 64];     // transpose staging
    const int tid = threadIdx.x;
    const int r0  = blockIdx.x * 8;   // 256 blocks x 8 rows

#pragma unroll
    for (int e = tid; e < 2048; e += 256)
        ((float4*)ws_)[e] = ((const float4*)w)[e];
    {
        int row = tid >> 5, c = tid & 31;
        float4 v = *(const float4*)&x[(size_t)(r0 + row) * 128 + c * 4];
        *(float4*)&xs[row * 132 + c * 4] = v;
    }
    __syncthreads();

    const int rl = tid >> 5;   // 0..7
    const int fg = tid & 31;   // 2 features
    float2 acc = {0.f, 0.f};
#pragma unroll
    for (int k4 = 0; k4 < 32; ++k4) {
        float4 xv = *(const float4*)&xs[rl * 132 + k4 * 4];
        const float* xp = &xv.x;
#pragma unroll
        for (int m = 0; m < 4; ++m) {
            float2 wv = *(const float2*)&ws_[(k4 * 4 + m) * 64 + 2 * fg];
            acc.x += xp[m] * wv.x; acc.y += xp[m] * wv.y;
        }
    }
    size_t o = (size_t)(r0 + rl) * 64 + 2 * fg;
    *(float2*)&xw[o] = acc;
    __half2 h2 = __floats2half2_rn(acc.x, acc.y);
    *(__half2*)&xwh[o] = h2;
    *(__half2*)&ts[rl * 64 + 2 * fg] = h2;
    __syncthreads();

    if (tid < 64) {
        const int f = tid;
        const int b = r0 >> 10;
        const int n0 = r0 & 1023;
        __half hv[8];
#pragma unroll
        for (int r = 0; r < 8; ++r) hv[r] = ts[r * 64 + f];
        *(half8_t*)&xwt[((size_t)(b * 64 + f)) * 1024 + n0] = *(half8_t*)hv;
    }
}

// ---------------- Kernel 2: fused distances + MFMA, 32x64 tiles -------------
// Block = (b, 32-row i-tile, 64-col j-tile). Grid 1024 = 2 x 32 x 16.
template <bool ATOMIC>
__global__ __launch_bounds__(256) void fused_gtv(const __half* __restrict__ xwh,
                                                 const __half* __restrict__ xwt,
                                                 const float* __restrict__ adj,
                                                 __half* __restrict__ part,
                                                 float* __restrict__ aout,
                                                 float* __restrict__ pdeg) {
    __shared__ __half xih[32 * HSTR];   // 4.6 KB [i][f], 16B-block swizzled
    __shared__ __half xjh[64 * HSTR];   // 9.2 KB [j][f], swizzled
    __shared__ __half xjt[64 * HSTR];   // 9.2 KB [f][j], linear (MFMA B)
    __shared__ __half wt [32 * HSTR];   // 4.6 KB [i][j], linear (MFMA A)

    const int tid = threadIdx.x;
    const int bx  = blockIdx.x;
    const int js  = bx & 15;
    const int it  = (bx >> 4) & 31;
    const int b   = bx >> 9;
    const int i0  = it * 32;
    const int j0  = js * 64;

    const __half* xhb = xwh + (size_t)b * 65536;
    const __half* xtb = xwt + (size_t)b * 65536;
    const float*  adjb = adj + (size_t)b * 1048576;

    const int ty = tid >> 4;   // 0..15 -> i rows 2ty..2ty+1
    const int tx = tid & 15;   // 0..15 -> j cols 4tx..4tx+3

    // prefetch adj 2x4 block (16 lanes x 16B = 256B contiguous per row)
    float4 av[2];
#pragma unroll
    for (int r = 0; r < 2; ++r)
        av[r] = *(const float4*)&adjb[(size_t)(i0 + 2 * ty + r) * 1024 + j0 + 4 * tx];

    // stage xih (256 x 16B, swizzled) + xjh (swizzled) + xjt (linear)
    {
        int row = tid >> 3, cb = tid & 7;   // 32 rows x 8 cb
        int sc = ((cb ^ ((row >> 2) & 7)) << 3);
        float4 vi = *(const float4*)&xhb[(i0 + row) * 64 + cb * 8];
        *(float4*)&xih[row * HSTR + sc] = vi;
    }
#pragma unroll
    for (int e = tid; e < 512; e += 256) {
        int row = e >> 3, cb = e & 7;
        int sc = ((cb ^ ((row >> 2) & 7)) << 3);
        float4 vj = *(const float4*)&xhb[(j0 + row) * 64 + cb * 8];
        *(float4*)&xjh[row * HSTR + sc] = vj;
        float4 vt = *(const float4*)&xtb[row * 1024 + j0 + cb * 8];  // row = f
        *(float4*)&xjt[row * HSTR + cb * 8] = vt;
    }
    __syncthreads();

    // ---- phase 1: 2x4 pairwise L1 distances, packed f16 ----
    __half2 acc[2][4];
#pragma unroll
    for (int r = 0; r < 2; ++r)
#pragma unroll
        for (int q = 0; q < 4; ++q) acc[r][q] = __floats2half2_rn(0.f, 0.f);

#pragma unroll
    for (int c = 0; c < 8; ++c) {
        // xih rows 2ty+r: (row>>2)&7 == (ty>>1)&7 for r in {0,1}
        const int ca = ((c ^ ((ty >> 1) & 7)) << 3);
        const int cb = ((c ^ (tx & 7)) << 3);
        float4 a[2], bb[4];
#pragma unroll
        for (int r = 0; r < 2; ++r)
            a[r] = *(const float4*)&xih[(2 * ty + r) * HSTR + ca];
#pragma unroll
        for (int q = 0; q < 4; ++q)
            bb[q] = *(const float4*)&xjh[(4 * tx + q) * HSTR + cb];
#pragma unroll
        for (int r = 0; r < 2; ++r) {
            const __half2* pa = (const __half2*)&a[r];
#pragma unroll
            for (int q = 0; q < 4; ++q) {
                const __half2* pb = (const __half2*)&bb[q];
#pragma unroll
                for (int m = 0; m < 4; ++m)
                    acc[r][q] = __hadd2(acc[r][q], __habs2(__hsub2(pa[m], pb[m])));
            }
        }
    }

    // w = adj * rcp(max(d,1e-3)), diag excluded; write f16 wt[i][j]; deg via shfl
    float dsum[2];
#pragma unroll
    for (int r = 0; r < 2; ++r) {
        const int gi = i0 + 2 * ty + r;
        float wv[4];
        dsum[r] = 0.f;
#pragma unroll
        for (int q = 0; q < 4; ++q) {
            float d = __low2float(acc[r][q]) + __high2float(acc[r][q]);
            float inv = __builtin_amdgcn_rcpf(fmaxf(d, 1e-3f));
            float v = (&av[r].x)[q] * inv;
            wv[q] = (gi == j0 + 4 * tx + q) ? 0.f : v;
            dsum[r] += wv[q];
        }
        float2 packed;
        ((__half2*)&packed)[0] = __floats2half2_rn(wv[0], wv[1]);
        ((__half2*)&packed)[1] = __floats2half2_rn(wv[2], wv[3]);
        *(float2*)&wt[(2 * ty + r) * HSTR + 4 * tx] = packed;
    }
#pragma unroll
    for (int r = 0; r < 2; ++r) {
#pragma unroll
        for (int m = 1; m < 16; m <<= 1)
            dsum[r] += __shfl_xor(dsum[r], m, 16);
    }
    if (tx == 0) {
#pragma unroll
        for (int r = 0; r < 2; ++r) {
            if (ATOMIC) atomicAdd(&pdeg[b * 1024 + i0 + 2 * ty + r], dsum[r]);
            else pdeg[(js * 2 + b) * 1024 + i0 + 2 * ty + r] = dsum[r];
        }
    }
    __syncthreads();

    // ---- phase 2: MFMA  P[32x64] = W[32xj64] x Xj[j64xf64] ----
    // 8 (m,n) positions, 4 waves x 2 each: wave w -> m = w&1, n in {2(w>>1), +1}
    const int wv_  = tid >> 6;
    const int lane = tid & 63;
    const int quad = lane >> 4;
    const int l15  = lane & 15;
    const int mt   = wv_ & 1;
    const int nb   = (wv_ >> 1) * 2;

    f32x4_t c[2] = {{0,0,0,0},{0,0,0,0}};
    half8_t a0 = *(half8_t*)&wt[(mt * 16 + l15) * HSTR + quad * 8];
    half8_t a1 = *(half8_t*)&wt[(mt * 16 + l15) * HSTR + 32 + quad * 8];
#pragma unroll
    for (int n = 0; n < 2; ++n) {
        half8_t b0 = *(half8_t*)&xjt[((nb + n) * 16 + l15) * HSTR + quad * 8];
        half8_t b1 = *(half8_t*)&xjt[((nb + n) * 16 + l15) * HSTR + 32 + quad * 8];
        c[n] = __builtin_amdgcn_mfma_f32_16x16x32_f16(a0, b0, c[n], 0, 0, 0);
        c[n] = __builtin_amdgcn_mfma_f32_16x16x32_f16(a1, b1, c[n], 0, 0, 0);
    }

    // epilogue: C row = mt*16 + quad*4 + r, col = (nb+n)*16 + l15
    if (ATOMIC) {
#pragma unroll
        for (int n = 0; n < 2; ++n)
#pragma unroll
            for (int r = 0; r < 4; ++r) {
                int row = mt * 16 + quad * 4 + r;
                atomicAdd(&aout[((size_t)b * 1024 + i0 + row) * 64 + (nb + n) * 16 + l15], c[n][r]);
            }
    } else {
        const size_t slot = (size_t)(js * 2 + b) * 65536;
#pragma unroll
        for (int n = 0; n < 2; ++n)
#pragma unroll
            for (int r = 0; r < 4; ++r) {
                int row = mt * 16 + quad * 4 + r;
                part[slot + (i0 + row) * 64 + (nb + n) * 16 + l15] = __float2half(c[n][r]);
            }
    }
}

// ---------------- Kernel 3: reduce partials + identity + bias ----------------
__global__ __launch_bounds__(256) void finish_gtv_v2(const float* __restrict__ xw,
                                                     const __half* __restrict__ part,
                                                     const float* __restrict__ pdeg,
                                                     const float* __restrict__ bias,
                                                     float* __restrict__ out) {
    int idx2 = blockIdx.x * 256 + threadIdx.x;  // 0..65535 float2 elements
    int f2 = idx2 & 31;          // half2 / float2 column index (f = 2*f2)
    int r  = idx2 >> 5;          // b*1024 + n
    int b  = r >> 10;
    int n  = r & 1023;

    float2 s = {0.f, 0.f};
    float dgs = 0.f;
    const __half2* p2 = (const __half2*)part;
#pragma unroll
    for (int js = 0; js < JS; ++js) {
        int sl = js * 2 + b;
        __half2 h = p2[(size_t)sl * 32768 + n * 32 + f2];
        float2 f = __half22float2(h);
        s.x += f.x; s.y += f.y;
        dgs += pdeg[sl * 1024 + n];
    }
    float2 xv = ((const float2*)xw)[idx2];
    float2 bv = ((const float2*)bias)[f2];
    float id = 1.f - dgs;
    float2 o;
    o.x = s.x + id * xv.x + bv.x;
    o.y = s.y + id * xv.y + bv.y;
    ((float2*)out)[idx2] = o;
}

__global__ __launch_bounds__(256) void finish_gtv_atomic(const float* __restrict__ xw,
                                                         const float* __restrict__ pdeg,
                                                         const float* __restrict__ bias,
                                                         float* __restrict__ out) {
    int idx = blockIdx.x * 256 + threadIdx.x;  // 0..131071
    int f = idx & 63;
    int r = idx >> 6;           // b*1024 + n
    out[idx] = out[idx] + (1.f - pdeg[r]) * xw[idx] + bias[f];
}

extern "C" void kernel_launch(void* const* d_in, const int* in_sizes, int n_in,
                              void* d_out, int out_size, void* d_ws, size_t ws_size,
                              hipStream_t stream) {
    const float* x    = (const float*)d_in[0];   // [2,1024,128]
    const float* adj  = (const float*)d_in[1];   // [2,1024,1024]
    const float* w    = (const float*)d_in[2];   // [128,64]
    const float* bias = (const float*)d_in[3];   // [64]
    float* out = (float*)d_out;                  // [2,1024,64]

    char* wsb = (char*)d_ws;
    float*  xw   = (float*)wsb;                      // 512 KB
    __half* xwh  = (__half*)(wsb + 512 * 1024);      // 256 KB  [b][n][f]
    __half* xwt  = (__half*)(wsb + 768 * 1024);      // 256 KB  [b][f][n]
    float*  pdeg = (float*)(wsb + 1024 * 1024);      // 128 KB (32 x 1024)
    __half* part = (__half*)(wsb + 1152 * 1024);     // 4 MB  (32 x 65536 f16)
    const size_t NEED = 1152 * 1024 + (size_t)32 * 65536 * 2;

    gemm_xw<<<256, 256, 0, stream>>>(x, w, xw, xwh, xwt);

    if (ws_size >= NEED) {
        fused_gtv<false><<<1024, 256, 0, stream>>>(xwh, xwt, adj, part, nullptr, pdeg);
        finish_gtv_v2<<<256, 256, 0, stream>>>(xw, part, pdeg, bias, out);
    } else {
        hipMemsetAsync(out, 0, 2 * 1024 * 64 * sizeof(float), stream);
        hipMemsetAsync(pdeg, 0, 2 * 1024 * sizeof(float), stream);
        fused_gtv<true><<<1024, 256, 0, stream>>>(xwh, xwt, adj, nullptr, out, pdeg);
        finish_gtv_atomic<<<512, 256, 0, stream>>>(xw, pdeg, bias, out);
    }
}